// Round 1
// 1258.187 us; speedup vs baseline: 1.0527x; 1.0527x over previous
//
#include <hip/hip_runtime.h>
#include <hip/hip_bf16.h>
#include <stdint.h>

#define BATCH 64
#define SEQ   2048
#define VDIM  1024
#define HDIM  1024
#define LDSB  24576   // shorts per pipeline buffer (48 KiB): A 128x64 + B 256x64 bf16

typedef __bf16 b8v __attribute__((ext_vector_type(8)));
typedef __bf16 b4v __attribute__((ext_vector_type(4)));
typedef float f32x4 __attribute__((ext_vector_type(4)));
typedef unsigned short u16x8 __attribute__((ext_vector_type(8)));

__device__ __forceinline__ float bf2f(unsigned short u) {
    union { unsigned int i; float f; } cv; cv.i = ((unsigned int)u) << 16; return cv.f;
}

// pack 2 fp32 -> 2 bf16 (RNE). Only used by the f32 fallback GEMM staging.
__device__ __forceinline__ unsigned int pack_bf16_2(float a, float b) {
#if __has_builtin(__builtin_amdgcn_cvt_pk_bf16_f32)
    auto t = __builtin_amdgcn_cvt_pk_bf16_f32(a, b);
    unsigned int r; __builtin_memcpy(&r, &t, 4); return r;
#else
    union { float f; unsigned int u; } ca, cb; ca.f = a; cb.f = b;
    unsigned int ra = ca.u + 0x7FFF + ((ca.u >> 16) & 1);
    unsigned int rb = cb.u + 0x7FFF + ((cb.u >> 16) & 1);
    return (ra >> 16) | (rb & 0xFFFF0000u);
#endif
}

__device__ __forceinline__ void gload_lds16(const unsigned short* g, unsigned short* l) {
    __builtin_amdgcn_global_load_lds(
        (const __attribute__((address_space(1))) unsigned int*)g,
        (__attribute__((address_space(3))) unsigned int*)l, 16, 0, 0);
}

// -------- fp32 -> bf16, 8 elems/thread (2x float4 load, 16B store) --------
__global__ __launch_bounds__(256) void cvt_bf16_kernel(
    const float* __restrict__ in, unsigned short* __restrict__ out, long n8)
{
    long g = (long)blockIdx.x * 256 + threadIdx.x;
    if (g >= n8) return;
    float4 a = *(const float4*)(in + g * 8);
    float4 b = *(const float4*)(in + g * 8 + 4);
    b8v o = {(__bf16)a.x, (__bf16)a.y, (__bf16)a.z, (__bf16)a.w,
             (__bf16)b.x, (__bf16)b.y, (__bf16)b.z, (__bf16)b.w};
    *(b8v*)(out + g * 8) = o;
}

// -------- hq[b][h] = q[b]·W_q[h] + b_q[h] + b_v[h] --------
// wave-per-h: Wq row is wave-uniform (scalarizes to s_load broadcast);
// q rows stream per-lane through L1. Fixes the fully-uncoalesced Wq reads.
__global__ __launch_bounds__(256) void hq_kernel(
    const float* __restrict__ q, const float* __restrict__ Wq,
    const float* __restrict__ bq, const float* __restrict__ bv,
    float* __restrict__ hq)
{
    const int h = blockIdx.x * 4 + (threadIdx.x >> 6);  // 256 blocks x 4 waves
    const int lane = threadIdx.x & 63;                  // = b
    const float4* qr = (const float4*)(q + ((size_t)lane << 10));
    const float4* wr = (const float4*)(Wq + ((size_t)h << 10));
    float acc = 0.f;
    #pragma unroll 8
    for (int k = 0; k < 256; ++k) {
        float4 wa = wr[k];   // wave-uniform
        float4 qa = qr[k];
        acc += qa.x*wa.x + qa.y*wa.y + qa.z*wa.z + qa.w*wa.w;
    }
    hq[((size_t)lane << 10) + h] = acc + bq[h] + bv[h];
}

// ======== fused deep-pipeline GEMM + tanh + Wo-contraction ========
// Tiles: BM=128 (rows of v), BN=256 (h), BK=64. 8 waves (2M x 4N), per-wave
// 64x64 output = acc[4][4] (same verified fragment->C mapping as before).
// 3-buffer LDS rotation: tile t computed from buf t%3 while tile t+2 stages
// into buf (t+2)%3 (free since end of tile t-1) -> counted vmcnt(6), no drain.
// LDS chunk-swizzle: 16B chunk index ^= (row&7), applied on the per-lane
// GLOBAL source address (linear gload_lds dest) and on the ds_read address.
__global__ __launch_bounds__(512, 2) void fused_8ph(
    const unsigned short* __restrict__ v, const unsigned short* __restrict__ Wv,
    const float* __restrict__ Wo, const float* __restrict__ hq,
    float* __restrict__ logit)
{
    __shared__ __align__(16) unsigned short lds[3 * LDSB];   // 144 KiB
    __shared__ float logit_lds[128];

    const int tid  = threadIdx.x;
    const int w    = tid >> 6;
    const int lane = tid & 63;
    const int col  = lane & 15;
    const int quad = lane >> 4;
    const int wm   = w >> 2;        // 0..1 : rows wm*64
    const int wn   = w & 3;         // 0..3 : cols wn*64

    // XCD-bijective chunked swizzle: 4096 blocks = 8 XCDs x 512.
    // Within an XCD, n varies fastest -> co-resident blocks share A-slices in L2.
    const int bid    = blockIdx.x;
    const int work   = ((bid & 7) << 9) + (bid >> 3);
    const int m_tile = work >> 2;   // 0..1023
    const int n_tile = work & 3;    // 0..3

    if (tid < 128) logit_lds[tid] = 0.f;

    f32x4 acc[4][4];
    #pragma unroll
    for (int i = 0; i < 4; ++i)
        #pragma unroll
        for (int j = 0; j < 4; ++j) acc[i][j] = (f32x4)(0.f);

    // ---- staging addressing (per-lane pre-swizzled source, linear LDS dest) ----
    const int rowoff = tid >> 3;                    // 0..63 row within 64-row round
    const int ch     = (tid & 7) ^ (rowoff & 7);    // swizzled 16B chunk of the row
    const unsigned short* gA = v  + (size_t)(m_tile * 128 + rowoff) * VDIM + (ch << 3);
    const unsigned short* gB = Wv + (size_t)(n_tile * 256 + rowoff) * VDIM + (ch << 3);
    const int ldA = tid << 3;                       // A region: + r*4096
    const int ldB = 8192 + (tid << 3);              // B region: + r*4096

    // ---- prologue: stage tiles 0 (buf0) and 1 (buf1) ----
    gload_lds16(gA,                  lds + ldA);
    gload_lds16(gA + 64*VDIM,        lds + 4096 + ldA);
    gload_lds16(gB,                  lds + ldB);
    gload_lds16(gB + 64*VDIM,        lds + 4096 + ldB);
    gload_lds16(gB + 128*VDIM,       lds + 8192 + ldB);
    gload_lds16(gB + 192*VDIM,       lds + 12288 + ldB);
    gload_lds16(gA + 64,             lds + LDSB + ldA);
    gload_lds16(gA + 64 + 64*VDIM,   lds + LDSB + 4096 + ldA);
    gload_lds16(gB + 64,             lds + LDSB + ldB);
    gload_lds16(gB + 64 + 64*VDIM,   lds + LDSB + 4096 + ldB);
    gload_lds16(gB + 64 + 128*VDIM,  lds + LDSB + 8192 + ldB);
    gload_lds16(gB + 64 + 192*VDIM,  lds + LDSB + 12288 + ldB);
    asm volatile("s_waitcnt vmcnt(6)" ::: "memory");   // tile 0 landed
    __builtin_amdgcn_s_barrier();

    // ---- fragment read bases (swizzled chunk: ((kk*4+quad) ^ (row&7)) ) ----
    const int aoffbase = (wm * 64 + col) * 64;          // + i*1024 + chunk*8
    const int boffbase = 8192 + (wn * 64 + col) * 64;   // + j*1024 + chunk*8
    const int axor     = col & 7;                       // == row&7 for all frags

    const unsigned short* gAs = gA + 128;   // staging base for tile t+2
    const unsigned short* gBs = gB + 128;
    int cbase = 0;          // compute buffer offset (shorts)
    int sbase = 2 * LDSB;   // stage buffer offset

    b8v aF[4], bF[4];

#define FRAG_LOAD(kkc)                                                          \
    {   const int co = ((((kkc) << 2) + quad) ^ axor) << 3;                     \
        _Pragma("unroll") for (int i = 0; i < 4; ++i)                           \
            aF[i] = *(const b8v*)(lds + cbase + aoffbase + i*1024 + co);        \
        _Pragma("unroll") for (int j = 0; j < 4; ++j)                           \
            bF[j] = *(const b8v*)(lds + cbase + boffbase + j*1024 + co);    }

#define MFMA16()                                                                \
    _Pragma("unroll") for (int i = 0; i < 4; ++i)                               \
        _Pragma("unroll") for (int j = 0; j < 4; ++j)                           \
            acc[i][j] = __builtin_amdgcn_mfma_f32_16x16x32_bf16(aF[i], bF[j], acc[i][j], 0, 0, 0);

    #pragma unroll 1
    for (int t = 0; t < 16; ++t) {
        // ---------- phase 0 (kk = 0) ----------
        FRAG_LOAD(0)
        if (t < 14) {
            gload_lds16(gAs,            lds + sbase + ldA);
            gload_lds16(gAs + 64*VDIM,  lds + sbase + 4096 + ldA);
            gload_lds16(gBs,            lds + sbase + ldB);
        }
        __builtin_amdgcn_s_barrier();
        asm volatile("s_waitcnt lgkmcnt(0)" ::: "memory");
        __builtin_amdgcn_sched_barrier(0);
        __builtin_amdgcn_s_setprio(1);
        MFMA16()
        __builtin_amdgcn_s_setprio(0);
        __builtin_amdgcn_s_barrier();

        // ---------- phase 1 (kk = 1) ----------
        FRAG_LOAD(1)
        if (t < 14) {
            gload_lds16(gBs + 64*VDIM,   lds + sbase + 4096 + ldB);
            gload_lds16(gBs + 128*VDIM,  lds + sbase + 8192 + ldB);
            gload_lds16(gBs + 192*VDIM,  lds + sbase + 12288 + ldB);
        }
        __builtin_amdgcn_s_barrier();
        asm volatile("s_waitcnt lgkmcnt(0)" ::: "memory");
        __builtin_amdgcn_sched_barrier(0);
        __builtin_amdgcn_s_setprio(1);
        MFMA16()
        __builtin_amdgcn_s_setprio(0);
        // end-of-tile: guarantee tile t+1 landed; keep tile t+2 in flight.
        if (t <= 13)      { asm volatile("s_waitcnt vmcnt(6)" ::: "memory"); }
        else if (t == 14) { asm volatile("s_waitcnt vmcnt(0)" ::: "memory"); }
        __builtin_amdgcn_s_barrier();

        gAs += 64; gBs += 64;
        cbase += LDSB; if (cbase == 3 * LDSB) cbase = 0;
        sbase += LDSB; if (sbase == 3 * LDSB) sbase = 0;
    }
#undef FRAG_LOAD
#undef MFMA16

    // ---- epilogue: x = acc + hq[b][h]; logit += Wo[h]*tanh(x), reduce over h ----
    // C row m = wm*64 + i*16 + quad*4 + r ; b = m & 63 = i*16+quad*4+r
    float rowsum[4][4];
    #pragma unroll
    for (int i = 0; i < 4; ++i)
        #pragma unroll
        for (int r = 0; r < 4; ++r) rowsum[i][r] = 0.f;
    #pragma unroll
    for (int j = 0; j < 4; ++j) {
        const int h = n_tile * 256 + wn * 64 + j * 16 + col;
        const float wo = Wo[h];
        #pragma unroll
        for (int i = 0; i < 4; ++i) {
            const int brow = i * 16 + quad * 4;
            #pragma unroll
            for (int r = 0; r < 4; ++r) {
                float x = acc[i][j][r] + hq[(brow + r) * HDIM + h];
                float t = __expf(2.f * x);
                rowsum[i][r] += wo * (1.f - 2.f / (t + 1.f));
            }
        }
    }
    #pragma unroll
    for (int off = 1; off < 16; off <<= 1)
        #pragma unroll
        for (int i = 0; i < 4; ++i)
            #pragma unroll
            for (int r = 0; r < 4; ++r)
                rowsum[i][r] += __shfl_xor(rowsum[i][r], off, 64);
    if (col == 0) {
        #pragma unroll
        for (int i = 0; i < 4; ++i)
            #pragma unroll
            for (int r = 0; r < 4; ++r)
                atomicAdd(&logit_lds[wm * 64 + i * 16 + quad * 4 + r], rowsum[i][r]);
    }
    __syncthreads();
    if (tid < 128) {
        const int b = tid & 63;
        const int s = m_tile * 2 + (tid >> 6);
        atomicAdd(&logit[b * SEQ + s], logit_lds[tid]);
    }
}

// ======== f32 fallback path (small workspace): unchanged structure ========
#define GEMM_EPILOGUE()                                                        \
    float rowsum[4][4];                                                        \
    _Pragma("unroll") for (int i = 0; i < 4; ++i)                              \
        _Pragma("unroll") for (int r = 0; r < 4; ++r) rowsum[i][r] = 0.f;      \
    _Pragma("unroll") for (int j = 0; j < 4; ++j) {                            \
        const int h = n_tile*128 + wave_n + j*16 + col;                        \
        const float wo = Wo[h];                                                \
        _Pragma("unroll") for (int i = 0; i < 4; ++i) {                        \
            const int brow = i*16 + quad*4;                                    \
            _Pragma("unroll") for (int r = 0; r < 4; ++r) {                    \
                float x = acc[i][j][r] + hq[(brow + r)*HDIM + h];              \
                float t = __expf(2.f * x);                                     \
                rowsum[i][r] += wo * (1.f - 2.f / (t + 1.f));                  \
            }                                                                  \
        }                                                                      \
    }                                                                          \
    _Pragma("unroll") for (int off = 1; off < 16; off <<= 1)                   \
        _Pragma("unroll") for (int i = 0; i < 4; ++i)                          \
            _Pragma("unroll") for (int r = 0; r < 4; ++r)                      \
                rowsum[i][r] += __shfl_xor(rowsum[i][r], off, 64);             \
    if (col == 0) {                                                            \
        _Pragma("unroll") for (int i = 0; i < 4; ++i)                          \
            _Pragma("unroll") for (int r = 0; r < 4; ++r)                      \
                atomicAdd(&logit_lds[wave_m + i*16 + quad*4 + r], rowsum[i][r]); \
    }                                                                          \
    __syncthreads();                                                           \
    if (tid < 128) {                                                           \
        const int b = tid & 63;                                                \
        const int s = m_tile*2 + (tid >> 6);                                   \
        atomicAdd(&logit[b*SEQ + s], logit_lds[tid]);                          \
    }

__global__ __launch_bounds__(256) void fused_f32(
    const float* __restrict__ v, const float* __restrict__ Wv,
    const float* __restrict__ Wo, const float* __restrict__ hq,
    float* __restrict__ logit)
{
    __shared__ __align__(16) unsigned short ldsA[128*32];
    __shared__ __align__(16) unsigned short ldsB[128*32];
    __shared__ float logit_lds[128];

    const int tid  = threadIdx.x;
    const int w    = tid >> 6;
    const int lane = tid & 63;
    const int col  = lane & 15;
    const int quad = lane >> 4;
    const int wave_m = (w >> 1) << 6;
    const int wave_n = (w & 1) << 6;
    const int n_tile = blockIdx.x;
    const int m_tile = blockIdx.y;

    if (tid < 128) logit_lds[tid] = 0.f;

    f32x4 acc[4][4];
    #pragma unroll
    for (int i = 0; i < 4; ++i)
        #pragma unroll
        for (int j = 0; j < 4; ++j) acc[i][j] = (f32x4)(0.f);

    const int srow8 = lane >> 3;
    const int scolf = (lane & 7) << 2;
    const float* gA = v  + (size_t)(m_tile * 128 + w*32 + srow8) * VDIM + scolf;
    const float* gB = Wv + (size_t)(n_tile * 128 + w*32 + srow8) * VDIM + scolf;
    unsigned short* lA = ldsA + (w*32 + srow8)*32 + ((lane & 7) << 2);
    unsigned short* lB = ldsB + (w*32 + srow8)*32 + ((lane & 7) << 2);

    float4 ra[4], rb[4];
    #pragma unroll
    for (int r = 0; r < 4; ++r) {
        ra[r] = *(const float4*)(gA + r*8*VDIM);
        rb[r] = *(const float4*)(gB + r*8*VDIM);
    }

    for (int kt = 0; kt < 32; ++kt) {
        __syncthreads();
        #pragma unroll
        for (int r = 0; r < 4; ++r) {
            uint2 pa = { pack_bf16_2(ra[r].x, ra[r].y), pack_bf16_2(ra[r].z, ra[r].w) };
            uint2 pb = { pack_bf16_2(rb[r].x, rb[r].y), pack_bf16_2(rb[r].z, rb[r].w) };
            *(uint2*)(lA + r*256) = pa;
            *(uint2*)(lB + r*256) = pb;
        }
        __syncthreads();

        if (kt < 31) {
            const int ko = (kt + 1) << 5;
            #pragma unroll
            for (int r = 0; r < 4; ++r) {
                ra[r] = *(const float4*)(gA + ko + r*8*VDIM);
                rb[r] = *(const float4*)(gB + ko + r*8*VDIM);
            }
        }

        b8v aF[4], bF[4];
        #pragma unroll
        for (int i = 0; i < 4; ++i)
            aF[i] = *(const b8v*)(ldsA + ((wave_m + i*16 + col) << 5) + (quad << 3));
        #pragma unroll
        for (int j = 0; j < 4; ++j)
            bF[j] = *(const b8v*)(ldsB + ((wave_n + j*16 + col) << 5) + (quad << 3));
        #pragma unroll
        for (int i = 0; i < 4; ++i)
            #pragma unroll
            for (int j = 0; j < 4; ++j)
                acc[i][j] = __builtin_amdgcn_mfma_f32_16x16x32_bf16(aF[i], bF[j], acc[i][j], 0, 0, 0);
    }

    GEMM_EPILOGUE()
}

// -------- softmax over S per b --------
__global__ __launch_bounds__(256) void softmax_kernel(float* __restrict__ logit,
                                                      float* __restrict__ pout)
{
    const int b = blockIdx.x, tid = threadIdx.x;
    float* row = logit + b * SEQ;
    __shared__ float red[4];

    float e[8];
    float lmax = -1e30f;
    #pragma unroll
    for (int k = 0; k < 8; ++k) { e[k] = row[tid + k*256]; lmax = fmaxf(lmax, e[k]); }
    #pragma unroll
    for (int off = 32; off > 0; off >>= 1) lmax = fmaxf(lmax, __shfl_xor(lmax, off, 64));
    if ((tid & 63) == 0) red[tid >> 6] = lmax;
    __syncthreads();
    lmax = fmaxf(fmaxf(red[0], red[1]), fmaxf(red[2], red[3]));
    __syncthreads();
    float lsum = 0.f;
    #pragma unroll
    for (int k = 0; k < 8; ++k) { e[k] = __expf(e[k] - lmax); lsum += e[k]; }
    #pragma unroll
    for (int off = 32; off > 0; off >>= 1) lsum += __shfl_xor(lsum, off, 64);
    if ((tid & 63) == 0) red[tid >> 6] = lsum;
    __syncthreads();
    lsum = red[0] + red[1] + red[2] + red[3];
    const float inv = 1.f / lsum;
    #pragma unroll
    for (int k = 0; k < 8; ++k) {
        const int s = tid + k*256;
        const float pv = e[k] * inv;
        row[s] = pv;
        pout[b*SEQ + s] = pv;
    }
}

// -------- ctx[b][:] = sum_s p[b][s] * v[s][b][:] (atomic into d_out) --------
__global__ __launch_bounds__(128) void ctx_f32(
    const float* __restrict__ v, const float* __restrict__ p, float* __restrict__ ctx)
{
    const int b = blockIdx.y, sc = blockIdx.x, tid = threadIdx.x;
    float acc[8];
    #pragma unroll
    for (int e = 0; e < 8; ++e) acc[e] = 0.f;
    for (int s = sc*128; s < sc*128 + 128; ++s) {
        const float pv = p[b*SEQ + s];
        const float4* vp = (const float4*)(v + (size_t)(s*64 + b) * VDIM + tid*8);
        float4 v0 = vp[0], v1 = vp[1];
        acc[0] = fmaf(pv, v0.x, acc[0]); acc[1] = fmaf(pv, v0.y, acc[1]);
        acc[2] = fmaf(pv, v0.z, acc[2]); acc[3] = fmaf(pv, v0.w, acc[3]);
        acc[4] = fmaf(pv, v1.x, acc[4]); acc[5] = fmaf(pv, v1.y, acc[5]);
        acc[6] = fmaf(pv, v1.z, acc[6]); acc[7] = fmaf(pv, v1.w, acc[7]);
    }
    #pragma unroll
    for (int e = 0; e < 8; ++e) atomicAdd(&ctx[b*VDIM + tid*8 + e], acc[e]);
}

__global__ __launch_bounds__(128) void ctx_bf16(
    const unsigned short* __restrict__ v, const float* __restrict__ p, float* __restrict__ ctx)
{
    const int b = blockIdx.y, sc = blockIdx.x, tid = threadIdx.x;
    float acc[8];
    #pragma unroll
    for (int e = 0; e < 8; ++e) acc[e] = 0.f;
    for (int s = sc*128; s < sc*128 + 128; ++s) {
        const float pv = p[b*SEQ + s];
        u16x8 val = *(const u16x8*)(v + (size_t)(s*64 + b) * VDIM + tid*8);
        #pragma unroll
        for (int e = 0; e < 8; ++e) acc[e] = fmaf(pv, bf2f(val[e]), acc[e]);
    }
    #pragma unroll
    for (int e = 0; e < 8; ++e) atomicAdd(&ctx[b*VDIM + tid*8 + e], acc[e]);
}

extern "C" void kernel_launch(void* const* d_in, const int* in_sizes, int n_in,
                              void* d_out, int out_size, void* d_ws, size_t ws_size,
                              hipStream_t stream)
{
    const float* q  = (const float*)d_in[0];
    const float* v  = (const float*)d_in[1];
    const float* Wv = (const float*)d_in[2];
    const float* bv = (const float*)d_in[3];
    const float* Wq = (const float*)d_in[4];
    const float* bq = (const float*)d_in[5];
    const float* Wo = (const float*)d_in[6];
    // d_in[7] = b_o: cancels under softmax shift-invariance

    float* hq_ws    = (float*)d_ws;                  // 65536 fp32
    float* logit_ws = hq_ws + 65536;                 // 131072 fp32
    float* ctx_ws   = logit_ws + 131072;             // 65536 fp32 (reserved, unused)
    unsigned short* vb  = (unsigned short*)(ctx_ws + 65536);   // SEQ*BATCH*VDIM bf16
    unsigned short* Wvb = vb + (size_t)SEQ*BATCH*VDIM;         // HDIM*VDIM bf16

    const size_t needA = (size_t)(65536 + 131072 + 65536) * 4
                       + ((size_t)SEQ*BATCH*VDIM + (size_t)HDIM*VDIM) * 2;
    const bool bigws = ws_size >= needA;

    float* out_ctx = (float*)d_out;          // [1,64,1024]
    float* out_p   = out_ctx + 65536;        // [64,2048]

    hipMemsetAsync(logit_ws, 0, 131072 * sizeof(float), stream);
    hipMemsetAsync(out_ctx, 0, 65536 * sizeof(float), stream);
    hq_kernel<<<256, 256, 0, stream>>>(q, Wq, bq, bv, hq_ws);

    if (bigws) {
        cvt_bf16_kernel<<<65536, 256, 0, stream>>>(v,  vb,  (long)SEQ*BATCH*VDIM/8);
        cvt_bf16_kernel<<<512,   256, 0, stream>>>(Wv, Wvb, (long)HDIM*VDIM/8);
        fused_8ph<<<4096, 512, 0, stream>>>(vb, Wvb, Wo, hq_ws, logit_ws);
        softmax_kernel<<<64, 256, 0, stream>>>(logit_ws, out_p);
        ctx_bf16<<<dim3(16, 64), 128, 0, stream>>>(vb, logit_ws, out_ctx);
    } else {
        fused_f32<<<dim3(8, 1024), 256, 0, stream>>>(v, Wv, Wo, hq_ws, logit_ws);
        softmax_kernel<<<64, 256, 0, stream>>>(logit_ws, out_p);
        ctx_f32<<<dim3(16, 64), 128, 0, stream>>>(v, logit_ws, out_ctx);
    }
}

// Round 2
// 1214.225 us; speedup vs baseline: 1.0908x; 1.0362x over previous
//
#include <hip/hip_runtime.h>
#include <hip/hip_bf16.h>
#include <stdint.h>

#define BATCH 64
#define SEQ   2048
#define VDIM  1024
#define HDIM  1024

typedef __bf16 b8v __attribute__((ext_vector_type(8)));
typedef __bf16 b4v __attribute__((ext_vector_type(4)));
typedef float f32x4 __attribute__((ext_vector_type(4)));
typedef unsigned short u16x8 __attribute__((ext_vector_type(8)));

__device__ __forceinline__ float bf2f(unsigned short u) {
    union { unsigned int i; float f; } cv; cv.i = ((unsigned int)u) << 16; return cv.f;
}

__device__ __forceinline__ float tanh_fast(float x) {
    float t = __expf(2.f * x);
#if __has_builtin(__builtin_amdgcn_rcpf)
    return 1.f - 2.f * __builtin_amdgcn_rcpf(t + 1.f);
#else
    return 1.f - 2.f / (t + 1.f);
#endif
}

// pack 2 fp32 -> 2 bf16 (RNE). Only used by the f32 fallback GEMM staging.
__device__ __forceinline__ unsigned int pack_bf16_2(float a, float b) {
#if __has_builtin(__builtin_amdgcn_cvt_pk_bf16_f32)
    auto t = __builtin_amdgcn_cvt_pk_bf16_f32(a, b);
    unsigned int r; __builtin_memcpy(&r, &t, 4); return r;
#else
    union { float f; unsigned int u; } ca, cb; ca.f = a; cb.f = b;
    unsigned int ra = ca.u + 0x7FFF + ((ca.u >> 16) & 1);
    unsigned int rb = cb.u + 0x7FFF + ((cb.u >> 16) & 1);
    return (ra >> 16) | (rb & 0xFFFF0000u);
#endif
}

__device__ __forceinline__ void gload_lds16(const unsigned short* g, unsigned short* l) {
    __builtin_amdgcn_global_load_lds(
        (const __attribute__((address_space(1))) unsigned int*)g,
        (__attribute__((address_space(3))) unsigned int*)l, 16, 0, 0);
}

// -------- fp32 -> bf16, 8 elems/thread --------
__global__ __launch_bounds__(256) void cvt_bf16_kernel(
    const float* __restrict__ in, unsigned short* __restrict__ out, long n8)
{
    long g = (long)blockIdx.x * 256 + threadIdx.x;
    if (g >= n8) return;
    float4 a = *(const float4*)(in + g * 8);
    float4 b = *(const float4*)(in + g * 8 + 4);
    b8v o = {(__bf16)a.x, (__bf16)a.y, (__bf16)a.z, (__bf16)a.w,
             (__bf16)b.x, (__bf16)b.y, (__bf16)b.z, (__bf16)b.w};
    *(b8v*)(out + g * 8) = o;
}

// -------- hq[b][h] = q[b]·W_q[h] + b_q[h] + b_v[h] --------
__global__ __launch_bounds__(256) void hq_kernel(
    const float* __restrict__ q, const float* __restrict__ Wq,
    const float* __restrict__ bq, const float* __restrict__ bv,
    float* __restrict__ hq)
{
    const int h = blockIdx.x * 4 + (threadIdx.x >> 6);
    const int lane = threadIdx.x & 63;                  // = b
    const float4* qr = (const float4*)(q + ((size_t)lane << 10));
    const float4* wr = (const float4*)(Wq + ((size_t)h << 10));
    float acc = 0.f;
    #pragma unroll 8
    for (int k = 0; k < 256; ++k) {
        float4 wa = wr[k];   // wave-uniform
        float4 qa = qr[k];
        acc += qa.x*wa.x + qa.y*wa.y + qa.z*wa.z + qa.w*wa.w;
    }
    hq[((size_t)lane << 10) + h] = acc + bq[h] + bv[h];
}

// ======== fused GEMM + tanh + Wo-contraction, BM=256 BN=256 BK=32 ========
// 8 waves (2M x 4N), per-wave 128x64 output (acc[8][4]) -> 42.7 FLOP per LDS
// byte (vs 32 at 64x64), the m201-verified geometry.
// LDS: 4-buffer rotation, 32 KB/buffer (A 16K + B 16K) = 128 KiB; depth-3
// staging with counted vmcnt(8), never 0 mid-loop.
// Layout: 16-row x 4-chunk subtiles; logical chunk (r,q) of a 256x32 tile
// lives at subtile (r>>4), slot q*16+(r&15). A wave's fragment read (rows
// R0..R0+15, chunk quad) is then lane-linear: 64 lanes x 16 B contiguous
// = zero bank conflicts, and staging dest is exactly tid*16 (gload_lds linear).
__global__ __launch_bounds__(512, 2) void fused_bk32(
    const unsigned short* __restrict__ v, const unsigned short* __restrict__ Wv,
    const float* __restrict__ Wo, const float* __restrict__ hq,
    float* __restrict__ logit)
{
    __shared__ __align__(16) unsigned short lds[65536];   // 128 KiB
    __shared__ float logit_lds[256];

    const int tid  = threadIdx.x;
    const int w    = tid >> 6;
    const int lane = tid & 63;
    const int col  = lane & 15;
    const int quad = lane >> 4;
    const int wm   = w >> 2;       // 0..1 : rows wm*128
    const int wn   = w & 3;        // 0..3 : cols wn*64

    // bijective XCD chunking (2048 % 8 == 0): the 4 n-tiles of one m-slice
    // are consecutive works -> same XCD -> A-slice shared in that XCD's L2.
    const int bid    = blockIdx.x;
    const int work   = ((bid & 7) << 8) + (bid >> 3);
    const int m_tile = work >> 2;           // 0..511
    const int n_tile = work & 3;            // 0..3

    if (tid < 256) logit_lds[tid] = 0.f;

    f32x4 acc[8][4];
    #pragma unroll
    for (int i = 0; i < 8; ++i)
        #pragma unroll
        for (int j = 0; j < 4; ++j) acc[i][j] = (f32x4)(0.f);

    // staging: thread covers logical (rA, qch) of rows 0..127; +128*VDIM for
    // the second half. Dest is linear tid*16 B within each 16 KB region.
    const int rA  = ((tid >> 6) << 4) + (tid & 15);   // 0..127
    const int qch = (tid >> 4) & 3;                   // 16B chunk 0..3
    const unsigned short* gAs = v  + (size_t)(m_tile * 256 + rA) * VDIM + (qch << 3);
    const unsigned short* gBs = Wv + (size_t)(n_tile * 256 + rA) * VDIM + (qch << 3);

    // prologue: stage tiles 0,1,2 into bufs 0,1,2
    {
        unsigned short* d = lds + (tid << 3);
        #pragma unroll
        for (int pt = 0; pt < 3; ++pt) {
            gload_lds16(gAs,             d);
            gload_lds16(gAs + 128*VDIM,  d + 4096);
            gload_lds16(gBs,             d + 8192);
            gload_lds16(gBs + 128*VDIM,  d + 12288);
            gAs += 32; gBs += 32; d += 16384;
        }
    }
    asm volatile("s_waitcnt vmcnt(8)" ::: "memory");   // tile 0 landed
    __builtin_amdgcn_s_barrier();

    const int aBase = (wm << 12) + (lane << 3);          // shorts
    const int bBase = 8192 + (wn << 11) + (lane << 3);

    #pragma unroll 1
    for (int t = 0; t < 32; ++t) {
        const unsigned short* bufp = lds + ((t & 3) << 14);
        unsigned short* stp = lds + (((t + 3) & 3) << 14) + (tid << 3);
        b8v aF[4], bF[4];

        // ---------- phase 0: i = 0..3 (reads B frags too) ----------
        #pragma unroll
        for (int j = 0; j < 4; ++j) bF[j] = *(const b8v*)(bufp + bBase + (j << 9));
        #pragma unroll
        for (int i = 0; i < 4; ++i) aF[i] = *(const b8v*)(bufp + aBase + (i << 9));
        if (t <= 28) {
            gload_lds16(gAs,            stp);
            gload_lds16(gAs + 128*VDIM, stp + 4096);
        }
        __builtin_amdgcn_s_barrier();
        asm volatile("s_waitcnt lgkmcnt(0)" ::: "memory");
        __builtin_amdgcn_sched_barrier(0);
        __builtin_amdgcn_s_setprio(1);
        #pragma unroll
        for (int i = 0; i < 4; ++i)
            #pragma unroll
            for (int j = 0; j < 4; ++j)
                acc[i][j] = __builtin_amdgcn_mfma_f32_16x16x32_bf16(aF[i], bF[j], acc[i][j], 0, 0, 0);
        __builtin_amdgcn_s_setprio(0);
        __builtin_amdgcn_s_barrier();

        // ---------- phase 1: i = 4..7 (B frags held in regs) ----------
        #pragma unroll
        for (int i = 0; i < 4; ++i) aF[i] = *(const b8v*)(bufp + aBase + ((i + 4) << 9));
        if (t <= 28) {
            gload_lds16(gBs,            stp + 8192);
            gload_lds16(gBs + 128*VDIM, stp + 12288);
            gAs += 32; gBs += 32;
        }
        __builtin_amdgcn_s_barrier();
        asm volatile("s_waitcnt lgkmcnt(0)" ::: "memory");
        __builtin_amdgcn_sched_barrier(0);
        __builtin_amdgcn_s_setprio(1);
        #pragma unroll
        for (int i = 0; i < 4; ++i)
            #pragma unroll
            for (int j = 0; j < 4; ++j)
                acc[i + 4][j] = __builtin_amdgcn_mfma_f32_16x16x32_bf16(aF[i], bF[j], acc[i + 4][j], 0, 0, 0);
        __builtin_amdgcn_s_setprio(0);
        // end-of-tile: tile t+1 must have landed; keep t+2/t+3 in flight.
        if (t < 29)       { asm volatile("s_waitcnt vmcnt(8)" ::: "memory"); }
        else if (t == 29) { asm volatile("s_waitcnt vmcnt(4)" ::: "memory"); }
        else if (t == 30) { asm volatile("s_waitcnt vmcnt(0)" ::: "memory"); }
        __builtin_amdgcn_s_barrier();
    }

    // ---- epilogue: logit += Wo[h]*tanh(acc + hq[b][h]), reduce over h ----
    // C row m = wm*128 + i*16 + quad*4 + r ; b = m & 63 (i and i+4 share b)
    float rowsum[8][4];
    #pragma unroll
    for (int i = 0; i < 8; ++i)
        #pragma unroll
        for (int r = 0; r < 4; ++r) rowsum[i][r] = 0.f;
    #pragma unroll
    for (int j = 0; j < 4; ++j) {
        const int h = n_tile * 256 + wn * 64 + j * 16 + col;
        const float wo = Wo[h];
        #pragma unroll
        for (int i = 0; i < 4; ++i) {
            #pragma unroll
            for (int r = 0; r < 4; ++r) {
                const float hqv = hq[(i * 16 + quad * 4 + r) * HDIM + h];
                float x0 = acc[i][j][r] + hqv;
                float x1 = acc[i + 4][j][r] + hqv;
                rowsum[i][r]     += wo * tanh_fast(x0);
                rowsum[i + 4][r] += wo * tanh_fast(x1);
            }
        }
    }
    #pragma unroll
    for (int off = 1; off < 16; off <<= 1)
        #pragma unroll
        for (int i = 0; i < 8; ++i)
            #pragma unroll
            for (int r = 0; r < 4; ++r)
                rowsum[i][r] += __shfl_xor(rowsum[i][r], off, 64);
    if (col == 0) {
        #pragma unroll
        for (int i = 0; i < 8; ++i)
            #pragma unroll
            for (int r = 0; r < 4; ++r)
                atomicAdd(&logit_lds[wm * 128 + i * 16 + quad * 4 + r], rowsum[i][r]);
    }
    __syncthreads();
    if (tid < 256) {
        const int b = tid & 63;
        const int s = m_tile * 4 + (tid >> 6);
        atomicAdd(&logit[b * SEQ + s], logit_lds[tid]);
    }
}

// ======== f32 fallback path (small workspace): unchanged ========
#define GEMM_EPILOGUE()                                                        \
    float rowsum[4][4];                                                        \
    _Pragma("unroll") for (int i = 0; i < 4; ++i)                              \
        _Pragma("unroll") for (int r = 0; r < 4; ++r) rowsum[i][r] = 0.f;      \
    _Pragma("unroll") for (int j = 0; j < 4; ++j) {                            \
        const int h = n_tile*128 + wave_n + j*16 + col;                        \
        const float wo = Wo[h];                                                \
        _Pragma("unroll") for (int i = 0; i < 4; ++i) {                        \
            const int brow = i*16 + quad*4;                                    \
            _Pragma("unroll") for (int r = 0; r < 4; ++r) {                    \
                float x = acc[i][j][r] + hq[(brow + r)*HDIM + h];              \
                float t = __expf(2.f * x);                                     \
                rowsum[i][r] += wo * (1.f - 2.f / (t + 1.f));                  \
            }                                                                  \
        }                                                                      \
    }                                                                          \
    _Pragma("unroll") for (int off = 1; off < 16; off <<= 1)                   \
        _Pragma("unroll") for (int i = 0; i < 4; ++i)                          \
            _Pragma("unroll") for (int r = 0; r < 4; ++r)                      \
                rowsum[i][r] += __shfl_xor(rowsum[i][r], off, 64);             \
    if (col == 0) {                                                            \
        _Pragma("unroll") for (int i = 0; i < 4; ++i)                          \
            _Pragma("unroll") for (int r = 0; r < 4; ++r)                      \
                atomicAdd(&logit_lds[wave_m + i*16 + quad*4 + r], rowsum[i][r]); \
    }                                                                          \
    __syncthreads();                                                           \
    if (tid < 128) {                                                           \
        const int b = tid & 63;                                                \
        const int s = m_tile*2 + (tid >> 6);                                   \
        atomicAdd(&logit[b*SEQ + s], logit_lds[tid]);                          \
    }

__global__ __launch_bounds__(256) void fused_f32(
    const float* __restrict__ v, const float* __restrict__ Wv,
    const float* __restrict__ Wo, const float* __restrict__ hq,
    float* __restrict__ logit)
{
    __shared__ __align__(16) unsigned short ldsA[128*32];
    __shared__ __align__(16) unsigned short ldsB[128*32];
    __shared__ float logit_lds[128];

    const int tid  = threadIdx.x;
    const int w    = tid >> 6;
    const int lane = tid & 63;
    const int col  = lane & 15;
    const int quad = lane >> 4;
    const int wave_m = (w >> 1) << 6;
    const int wave_n = (w & 1) << 6;
    const int n_tile = blockIdx.x;
    const int m_tile = blockIdx.y;

    if (tid < 128) logit_lds[tid] = 0.f;

    f32x4 acc[4][4];
    #pragma unroll
    for (int i = 0; i < 4; ++i)
        #pragma unroll
        for (int j = 0; j < 4; ++j) acc[i][j] = (f32x4)(0.f);

    const int srow8 = lane >> 3;
    const int scolf = (lane & 7) << 2;
    const float* gA = v  + (size_t)(m_tile * 128 + w*32 + srow8) * VDIM + scolf;
    const float* gB = Wv + (size_t)(n_tile * 128 + w*32 + srow8) * VDIM + scolf;
    unsigned short* lA = ldsA + (w*32 + srow8)*32 + ((lane & 7) << 2);
    unsigned short* lB = ldsB + (w*32 + srow8)*32 + ((lane & 7) << 2);

    float4 ra[4], rb[4];
    #pragma unroll
    for (int r = 0; r < 4; ++r) {
        ra[r] = *(const float4*)(gA + r*8*VDIM);
        rb[r] = *(const float4*)(gB + r*8*VDIM);
    }

    for (int kt = 0; kt < 32; ++kt) {
        __syncthreads();
        #pragma unroll
        for (int r = 0; r < 4; ++r) {
            uint2 pa = { pack_bf16_2(ra[r].x, ra[r].y), pack_bf16_2(ra[r].z, ra[r].w) };
            uint2 pb = { pack_bf16_2(rb[r].x, rb[r].y), pack_bf16_2(rb[r].z, rb[r].w) };
            *(uint2*)(lA + r*256) = pa;
            *(uint2*)(lB + r*256) = pb;
        }
        __syncthreads();

        if (kt < 31) {
            const int ko = (kt + 1) << 5;
            #pragma unroll
            for (int r = 0; r < 4; ++r) {
                ra[r] = *(const float4*)(gA + ko + r*8*VDIM);
                rb[r] = *(const float4*)(gB + ko + r*8*VDIM);
            }
        }

        b8v aF[4], bF[4];
        #pragma unroll
        for (int i = 0; i < 4; ++i)
            aF[i] = *(const b8v*)(ldsA + ((wave_m + i*16 + col) << 5) + (quad << 3));
        #pragma unroll
        for (int j = 0; j < 4; ++j)
            bF[j] = *(const b8v*)(ldsB + ((wave_n + j*16 + col) << 5) + (quad << 3));
        #pragma unroll
        for (int i = 0; i < 4; ++i)
            #pragma unroll
            for (int j = 0; j < 4; ++j)
                acc[i][j] = __builtin_amdgcn_mfma_f32_16x16x32_bf16(aF[i], bF[j], acc[i][j], 0, 0, 0);
    }

    GEMM_EPILOGUE()
}

// -------- softmax over S per b --------
__global__ __launch_bounds__(256) void softmax_kernel(float* __restrict__ logit,
                                                      float* __restrict__ pout)
{
    const int b = blockIdx.x, tid = threadIdx.x;
    float* row = logit + b * SEQ;
    __shared__ float red[4];

    float e[8];
    float lmax = -1e30f;
    #pragma unroll
    for (int k = 0; k < 8; ++k) { e[k] = row[tid + k*256]; lmax = fmaxf(lmax, e[k]); }
    #pragma unroll
    for (int off = 32; off > 0; off >>= 1) lmax = fmaxf(lmax, __shfl_xor(lmax, off, 64));
    if ((tid & 63) == 0) red[tid >> 6] = lmax;
    __syncthreads();
    lmax = fmaxf(fmaxf(red[0], red[1]), fmaxf(red[2], red[3]));
    __syncthreads();
    float lsum = 0.f;
    #pragma unroll
    for (int k = 0; k < 8; ++k) { e[k] = __expf(e[k] - lmax); lsum += e[k]; }
    #pragma unroll
    for (int off = 32; off > 0; off >>= 1) lsum += __shfl_xor(lsum, off, 64);
    if ((tid & 63) == 0) red[tid >> 6] = lsum;
    __syncthreads();
    lsum = red[0] + red[1] + red[2] + red[3];
    const float inv = 1.f / lsum;
    #pragma unroll
    for (int k = 0; k < 8; ++k) {
        const int s = tid + k*256;
        const float pv = e[k] * inv;
        row[s] = pv;
        pout[b*SEQ + s] = pv;
    }
}

// -------- ctx[b][:] = sum_s p[b][s] * v[s][b][:] (into workspace) --------
__global__ __launch_bounds__(128) void ctx_f32(
    const float* __restrict__ v, const float* __restrict__ p, float* __restrict__ ctx)
{
    const int b = blockIdx.y, sc = blockIdx.x, tid = threadIdx.x;
    float acc[8];
    #pragma unroll
    for (int e = 0; e < 8; ++e) acc[e] = 0.f;
    for (int s = sc*128; s < sc*128 + 128; ++s) {
        const float pv = p[b*SEQ + s];
        const float4* vp = (const float4*)(v + (size_t)(s*64 + b) * VDIM + tid*8);
        float4 v0 = vp[0], v1 = vp[1];
        acc[0] = fmaf(pv, v0.x, acc[0]); acc[1] = fmaf(pv, v0.y, acc[1]);
        acc[2] = fmaf(pv, v0.z, acc[2]); acc[3] = fmaf(pv, v0.w, acc[3]);
        acc[4] = fmaf(pv, v1.x, acc[4]); acc[5] = fmaf(pv, v1.y, acc[5]);
        acc[6] = fmaf(pv, v1.z, acc[6]); acc[7] = fmaf(pv, v1.w, acc[7]);
    }
    #pragma unroll
    for (int e = 0; e < 8; ++e) atomicAdd(&ctx[b*VDIM + tid*8 + e], acc[e]);
}

__global__ __launch_bounds__(128) void ctx_bf16(
    const unsigned short* __restrict__ v, const float* __restrict__ p, float* __restrict__ ctx)
{
    const int b = blockIdx.y, sc = blockIdx.x, tid = threadIdx.x;
    float acc[8];
    #pragma unroll
    for (int e = 0; e < 8; ++e) acc[e] = 0.f;
    for (int s = sc*128; s < sc*128 + 128; ++s) {
        const float pv = p[b*SEQ + s];
        u16x8 val = *(const u16x8*)(v + (size_t)(s*64 + b) * VDIM + tid*8);
        #pragma unroll
        for (int e = 0; e < 8; ++e) acc[e] = fmaf(pv, bf2f(val[e]), acc[e]);
    }
    #pragma unroll
    for (int e = 0; e < 8; ++e) atomicAdd(&ctx[b*VDIM + tid*8 + e], acc[e]);
}

__global__ __launch_bounds__(256) void copy_kernel(const float* __restrict__ src,
                                                   float* __restrict__ dst)
{
    int g = blockIdx.x * 256 + threadIdx.x;
    dst[g] = src[g];
}

extern "C" void kernel_launch(void* const* d_in, const int* in_sizes, int n_in,
                              void* d_out, int out_size, void* d_ws, size_t ws_size,
                              hipStream_t stream)
{
    const float* q  = (const float*)d_in[0];
    const float* v  = (const float*)d_in[1];
    const float* Wv = (const float*)d_in[2];
    const float* bv = (const float*)d_in[3];
    const float* Wq = (const float*)d_in[4];
    const float* bq = (const float*)d_in[5];
    const float* Wo = (const float*)d_in[6];
    // d_in[7] = b_o: cancels under softmax shift-invariance

    float* hq_ws    = (float*)d_ws;                  // 65536 fp32
    float* logit_ws = hq_ws + 65536;                 // 131072 fp32
    float* ctx_ws   = logit_ws + 131072;             // 65536 fp32
    unsigned short* vb  = (unsigned short*)(ctx_ws + 65536);   // SEQ*BATCH*VDIM bf16
    unsigned short* Wvb = vb + (size_t)SEQ*BATCH*VDIM;         // HDIM*VDIM bf16

    const size_t needA = (size_t)(65536 + 131072 + 65536) * 4
                       + ((size_t)SEQ*BATCH*VDIM + (size_t)HDIM*VDIM) * 2;
    const bool bigws = ws_size >= needA;

    float* out_ctx = (float*)d_out;          // [1,64,1024]
    float* out_p   = out_ctx + 65536;        // [64,2048]

    hipMemsetAsync(logit_ws, 0, (131072 + 65536) * sizeof(float), stream);
    hq_kernel<<<256, 256, 0, stream>>>(q, Wq, bq, bv, hq_ws);

    if (bigws) {
        cvt_bf16_kernel<<<65536, 256, 0, stream>>>(v,  vb,  (long)SEQ*BATCH*VDIM/8);
        cvt_bf16_kernel<<<512,   256, 0, stream>>>(Wv, Wvb, (long)HDIM*VDIM/8);
        fused_bk32<<<2048, 512, 0, stream>>>(vb, Wvb, Wo, hq_ws, logit_ws);
        softmax_kernel<<<64, 256, 0, stream>>>(logit_ws, out_p);
        ctx_bf16<<<dim3(16, 64), 128, 0, stream>>>(vb, logit_ws, ctx_ws);
    } else {
        fused_f32<<<dim3(8, 1024), 256, 0, stream>>>(v, Wv, Wo, hq_ws, logit_ws);
        softmax_kernel<<<64, 256, 0, stream>>>(logit_ws, out_p);
        ctx_f32<<<dim3(16, 64), 128, 0, stream>>>(v, logit_ws, ctx_ws);
    }
    copy_kernel<<<256, 256, 0, stream>>>(ctx_ws, out_ctx);
}